// Round 2
// baseline (328.667 us; speedup 1.0000x reference)
//
#include <hip/hip_runtime.h>
#include <hip/hip_bf16.h>

#define NB 32
#define NN 2048
#define DD 64
#define NC 64
#define LOG2E 1.44269504088896340736f

typedef __attribute__((ext_vector_type(8))) short short8;
typedef __attribute__((ext_vector_type(4))) float f32x4;

__device__ __forceinline__ short f2bf(float x) {
  __bf16 h = (__bf16)x;
  return __builtin_bit_cast(short, h);
}

__device__ __forceinline__ float fast_exp2(float x) {
#if __has_builtin(__builtin_amdgcn_exp2f)
  return __builtin_amdgcn_exp2f(x);
#else
  return exp2f(x);
#endif
}

// ---------- prep 1: x fp32 -> xbf (row-major bf16) + xT (per-batch [D][N] bf16)
__global__ __launch_bounds__(256) void prep_x(const float* __restrict__ x,
                                              short* __restrict__ xbf,
                                              short* __restrict__ xT) {
  __shared__ short t[64 * 72];
  const int tid = threadIdx.x;
  const int n0 = blockIdx.x * 64;
  const int b = blockIdx.y;
  const int r = tid >> 2;   // 0..63: row within tile (pass 1) / d column (pass 2)
  const int cg = tid & 3;   // 16-wide column group

  const float* src = x + ((size_t)b * NN + n0 + r) * DD + cg * 16;
  short8 v[2];
#pragma unroll
  for (int h = 0; h < 2; ++h) {
    float4 f0 = ((const float4*)src)[h * 2];
    float4 f1 = ((const float4*)src)[h * 2 + 1];
    short8 a;
    a[0] = f2bf(f0.x); a[1] = f2bf(f0.y); a[2] = f2bf(f0.z); a[3] = f2bf(f0.w);
    a[4] = f2bf(f1.x); a[5] = f2bf(f1.y); a[6] = f2bf(f1.z); a[7] = f2bf(f1.w);
    v[h] = a;
  }
  short* dst = xbf + ((size_t)b * NN + n0 + r) * DD + cg * 16;
  ((short8*)dst)[0] = v[0];
  ((short8*)dst)[1] = v[1];
  *(short8*)&t[r * 72 + cg * 16] = v[0];
  *(short8*)&t[r * 72 + cg * 16 + 8] = v[1];
  __syncthreads();
  // transposed read: thread owns column d=r, source rows cg*16..cg*16+15
  short8 o0, o1;
#pragma unroll
  for (int i = 0; i < 8; ++i) o0[i] = t[(cg * 16 + i) * 72 + r];
#pragma unroll
  for (int i = 0; i < 8; ++i) o1[i] = t[(cg * 16 + 8 + i) * 72 + r];
  short* dstT = xT + ((size_t)b * DD + r) * NN + n0 + cg * 16;
  ((short8*)dstT)[0] = o0;
  ((short8*)dstT)[1] = o1;
}

// ---------- prep 2: adj int32 -> bitmask (bit j of word w = adj[w*64+j] > 0)
__global__ __launch_bounds__(256) void prep_adj(const int* __restrict__ adj,
                                                unsigned long long* __restrict__ bits) {
  const int i = blockIdx.x * 256 + threadIdx.x;
  unsigned long long m = __ballot(adj[i] > 0);
  if ((threadIdx.x & 63) == 0) bits[i >> 6] = m;
}

// ---------- main: flash attention, no block-level barriers, no running max
__global__ __launch_bounds__(256, 4) void gat_flash2(
    const float* __restrict__ x, const short* __restrict__ xbf,
    const short* __restrict__ xT, const unsigned long long* __restrict__ adjb,
    float* __restrict__ out) {
  __shared__ short sP[4][16 * 72];  // per-wave P round-trip (bf16)

  const int tid = threadIdx.x;
  const int w = tid >> 6;
  const int l = tid & 63;
  const int lane16 = l & 15;
  const int quad = l >> 4;
  const int qtile = blockIdx.x;
  const int b = blockIdx.y;

  // Q A-frags from fp32 x, pre-scaled by (1/8)*log2(e)
  const int qrow = qtile * 64 + w * 16 + lane16;
  const float* qp = x + ((size_t)b * NN + qrow) * DD;
  const float qs = 0.125f * LOG2E;
  short8 aq[2];
#pragma unroll
  for (int ks = 0; ks < 2; ++ks) {
    const float4* p4 = (const float4*)(qp + ks * 32 + quad * 8);
    float4 v0 = p4[0], v1 = p4[1];
    short8 a;
    a[0] = f2bf(v0.x * qs); a[1] = f2bf(v0.y * qs);
    a[2] = f2bf(v0.z * qs); a[3] = f2bf(v0.w * qs);
    a[4] = f2bf(v1.x * qs); a[5] = f2bf(v1.y * qs);
    a[6] = f2bf(v1.z * qs); a[7] = f2bf(v1.w * qs);
    aq[ks] = a;
  }

  f32x4 acc[4] = {{0.f, 0.f, 0.f, 0.f}, {0.f, 0.f, 0.f, 0.f},
                  {0.f, 0.f, 0.f, 0.f}, {0.f, 0.f, 0.f, 0.f}};
  float lpart[4] = {0.f, 0.f, 0.f, 0.f};

  const int qrow_base = qtile * 64 + w * 16 + quad * 4;  // + r
  const short* xb_b = xbf + (size_t)b * NN * DD;
  const short* xT_b = xT + (size_t)b * DD * NN;
  short* sPw = sP[w];

  for (int kb = 0; kb < NN; kb += NC) {
    // adjacency bit-words for this wave's 16x64 S-tile
    uint2 abits[4];
#pragma unroll
    for (int r = 0; r < 4; ++r)
      abits[r] = ((const uint2*)adjb)[(size_t)(qrow_base + r) * (NN / 64) + (kb >> 6)];

    // ---- S = Q K^T (exp2 units); B-frags straight from global bf16 ----
    f32x4 s[4] = {{0.f, 0.f, 0.f, 0.f}, {0.f, 0.f, 0.f, 0.f},
                  {0.f, 0.f, 0.f, 0.f}, {0.f, 0.f, 0.f, 0.f}};
#pragma unroll
    for (int ks = 0; ks < 2; ++ks)
#pragma unroll
      for (int nt = 0; nt < 4; ++nt) {
        short8 bk = *(const short8*)&xb_b[(size_t)(kb + nt * 16 + lane16) * DD +
                                          ks * 32 + quad * 8];
        s[nt] = __builtin_amdgcn_mfma_f32_16x16x32_bf16(aq[ks], bk, s[nt], 0, 0, 0);
      }

    // ---- masked exp2 (no running max), deferred row-sum ----
#pragma unroll
    for (int r = 0; r < 4; ++r) {
      const unsigned sx = abits[r].x >> lane16;  // nt0 bit at 0, nt1 at 16
      const unsigned sy = abits[r].y >> lane16;  // nt2 bit at 0, nt3 at 16
#pragma unroll
      for (int nt = 0; nt < 4; ++nt) {
        const unsigned bit = ((nt < 2 ? sx : sy) >> ((nt & 1) * 16)) & 1u;
        float e = fast_exp2(s[nt][r]);
        float p = bit ? e : 0.f;
        lpart[r] += p;
        sPw[(quad * 4 + r) * 72 + nt * 16 + lane16] = f2bf(p);
      }
    }

    // ---- O^T += V^T P^T : A = V^T frag (from xT), B = P (A-layout data) ----
#pragma unroll
    for (int ks = 0; ks < 2; ++ks) {
      short8 ap = *(const short8*)&sPw[lane16 * 72 + ks * 32 + quad * 8];
#pragma unroll
      for (int dt = 0; dt < 4; ++dt) {
        short8 bv = *(const short8*)&xT_b[(size_t)(dt * 16 + lane16) * NN + kb +
                                          ks * 32 + quad * 8];
        acc[dt] = __builtin_amdgcn_mfma_f32_16x16x32_bf16(bv, ap, acc[dt], 0, 0, 0);
      }
    }
  }

  // ---- reduce row-sums across the 16 lanes of each quad group ----
#pragma unroll
  for (int r = 0; r < 4; ++r)
#pragma unroll
    for (int off = 8; off >= 1; off >>= 1)
      lpart[r] += __shfl_xor(lpart[r], off, 64);

  // redistribute: this lane's query row is lane16; its l lives in quad
  // group (lane16>>2), register (lane16&3)
  float lq = 0.f;
#pragma unroll
  for (int r = 0; r < 4; ++r) {
    float t = __shfl(lpart[r], (lane16 >> 2) * 16, 64);
    lq = ((lane16 & 3) == r) ? t : lq;
  }
  const float inv = 1.0f / lq;

  // ---- epilogue: lane holds O[query=lane16][d = dt*16 + quad*4 + g] ----
  float* orow = out + ((size_t)b * NN + qrow) * DD;
#pragma unroll
  for (int dt = 0; dt < 4; ++dt) {
    float4 o;
    o.x = acc[dt][0] * inv;
    o.y = acc[dt][1] * inv;
    o.z = acc[dt][2] * inv;
    o.w = acc[dt][3] * inv;
    *(float4*)(orow + dt * 16 + quad * 4) = o;
  }
}

extern "C" void kernel_launch(void* const* d_in, const int* in_sizes, int n_in,
                              void* d_out, int out_size, void* d_ws,
                              size_t ws_size, hipStream_t stream) {
  const float* x = (const float*)d_in[0];
  const int* adj = (const int*)d_in[1];
  float* out = (float*)d_out;

  short* xbf = (short*)d_ws;                          // 8 MB
  short* xT = xbf + (size_t)NB * NN * DD;             // 8 MB
  unsigned long long* adjb =
      (unsigned long long*)(xT + (size_t)NB * NN * DD);  // 512 KB

  prep_x<<<dim3(NN / 64, NB), 256, 0, stream>>>(x, xbf, xT);
  prep_adj<<<(NN * NN) / 256, 256, 0, stream>>>(adj, adjb);
  gat_flash2<<<dim3(NN / 64, NB), 256, 0, stream>>>(x, xbf, xT, adjb, out);
}

// Round 4
// 192.987 us; speedup vs baseline: 1.7031x; 1.7031x over previous
//
#include <hip/hip_runtime.h>
#include <hip/hip_bf16.h>

#define NB 32
#define NN 2048
#define DD 64
#define NCH 32
#define LOG2E 1.44269504088896340736f

typedef __attribute__((ext_vector_type(8))) short short8;
typedef __attribute__((ext_vector_type(4))) short short4v;
typedef __attribute__((ext_vector_type(4))) float f32x4;

// v_mfma_f32_16x16x16_bf16 (A/B = 4 bf16 in 2 VGPRs) — direct builtin; do
// NOT gate on __has_builtin (false in the host pass, bit us in round 3).
#define MFMA16(A, B, C) \
  __builtin_amdgcn_mfma_f32_16x16x16bf16_1k((A), (B), (C), 0, 0, 0)

#define GLOAD_LDS16(gp, lp)                                                   \
  __builtin_amdgcn_global_load_lds(                                          \
      (const __attribute__((address_space(1))) void*)(gp),                   \
      (__attribute__((address_space(3))) void*)(lp), 16, 0, 0)

__device__ __forceinline__ short f2bf(float x) {
  __bf16 h = (__bf16)x;
  return __builtin_bit_cast(short, h);
}

__device__ __forceinline__ float fast_exp2(float x) {
  return exp2f(x);  // lowers to v_exp_f32 on gfx950
}

// ---------- prep 1: x fp32 -> xbf (row-major bf16) + xT (per-batch [D][N] bf16)
__global__ __launch_bounds__(256) void prep_x(const float* __restrict__ x,
                                              short* __restrict__ xbf,
                                              short* __restrict__ xT) {
  __shared__ short t[64 * 72];
  const int tid = threadIdx.x;
  const int n0 = blockIdx.x * 64;
  const int b = blockIdx.y;
  const int r = tid >> 2;
  const int cg = tid & 3;

  const float* src = x + ((size_t)b * NN + n0 + r) * DD + cg * 16;
  short8 v[2];
#pragma unroll
  for (int h = 0; h < 2; ++h) {
    float4 f0 = ((const float4*)src)[h * 2];
    float4 f1 = ((const float4*)src)[h * 2 + 1];
    short8 a;
    a[0] = f2bf(f0.x); a[1] = f2bf(f0.y); a[2] = f2bf(f0.z); a[3] = f2bf(f0.w);
    a[4] = f2bf(f1.x); a[5] = f2bf(f1.y); a[6] = f2bf(f1.z); a[7] = f2bf(f1.w);
    v[h] = a;
  }
  short* dst = xbf + ((size_t)b * NN + n0 + r) * DD + cg * 16;
  ((short8*)dst)[0] = v[0];
  ((short8*)dst)[1] = v[1];
  *(short8*)&t[r * 72 + cg * 16] = v[0];
  *(short8*)&t[r * 72 + cg * 16 + 8] = v[1];
  __syncthreads();
  short8 o0, o1;
#pragma unroll
  for (int i = 0; i < 8; ++i) o0[i] = t[(cg * 16 + i) * 72 + r];
#pragma unroll
  for (int i = 0; i < 8; ++i) o1[i] = t[(cg * 16 + 8 + i) * 72 + r];
  short* dstT = xT + ((size_t)b * DD + r) * NN + n0 + cg * 16;
  ((short8*)dstT)[0] = o0;
  ((short8*)dstT)[1] = o1;
}

// ---------- prep 2: adj int32 -> bitmask
__global__ __launch_bounds__(256) void prep_adj(const int* __restrict__ adj,
                                                unsigned long long* __restrict__ bits) {
  const int i = blockIdx.x * 256 + threadIdx.x;
  unsigned long long m = __ballot(adj[i] > 0);
  if ((threadIdx.x & 63) == 0) bits[i >> 6] = m;
}

// ---------- main: S^T formulation, LDS-staged K/V (swizzled), register-only P
// Block = 4 waves x 64 q-rows = 256 q-rows; grid = (NN/256, NB) = 256 blocks.
__global__ __launch_bounds__(256, 1) void gat_flash3(
    const float* __restrict__ x, const short* __restrict__ xbf,
    const short* __restrict__ xT, const unsigned long long* __restrict__ adjb,
    float* __restrict__ out) {
  __shared__ short sK[2][64 * 64];  // swizzled: 16B block j' = j ^ (row&7)
  __shared__ short sV[2][64 * 64];

  const int tid = threadIdx.x;
  const int w = tid >> 6;
  const int l = tid & 63;
  const int lane16 = l & 15;
  const int quad = l >> 4;
  const int b = blockIdx.y;
  const int qbase = blockIdx.x * 256 + w * 64;

  const short* xb_b = xbf + (size_t)b * NN * DD;
  const short* xT_b = xT + (size_t)b * DD * NN;

  // staging geometry (identical formula for stage & read => self-consistent)
  const int st_row = (l >> 3);            // + (i*4+w)*8
  const int st_j = (l & 7) ^ (l >> 3);    // global 16B-block for this lane

  // ---- Q B-frags (n=lane16=q, k=quad*8+j=d), pre-scaled by (1/8)*log2e ----
  const float qs = 0.125f * LOG2E;
  short8 qf[4][2];
#pragma unroll
  for (int qt = 0; qt < 4; ++qt) {
    const float* qp = x + ((size_t)b * NN + qbase + qt * 16 + lane16) * DD;
#pragma unroll
    for (int ks = 0; ks < 2; ++ks) {
      float4 v0 = *(const float4*)(qp + ks * 32 + quad * 8);
      float4 v1 = *(const float4*)(qp + ks * 32 + quad * 8 + 4);
      short8 a;
      a[0] = f2bf(v0.x * qs); a[1] = f2bf(v0.y * qs);
      a[2] = f2bf(v0.z * qs); a[3] = f2bf(v0.w * qs);
      a[4] = f2bf(v1.x * qs); a[5] = f2bf(v1.y * qs);
      a[6] = f2bf(v1.z * qs); a[7] = f2bf(v1.w * qs);
      qf[qt][ks] = a;
    }
  }

  f32x4 acc[4][4];  // [qt][dt] O^T tiles: row=d=quad*4+reg, col=q=lane16
#pragma unroll
  for (int qt = 0; qt < 4; ++qt)
#pragma unroll
    for (int dt = 0; dt < 4; ++dt) acc[qt][dt] = {0.f, 0.f, 0.f, 0.f};
  float lpart[4] = {0.f, 0.f, 0.f, 0.f};

  // ---- stage chunk 0 into buf 0 ----
#pragma unroll
  for (int i = 0; i < 2; ++i) {
    const int base = (i * 4 + w) * 512;  // elements (1KB per wave-iter)
    const int row = (i * 4 + w) * 8 + st_row;
    GLOAD_LDS16(xb_b + (size_t)row * DD + st_j * 8, &sK[0][base]);
    GLOAD_LDS16(xT_b + (size_t)row * NN + st_j * 8, &sV[0][base]);
  }
  __syncthreads();

  for (int c = 0; c < NCH; ++c) {
    const int cur = c & 1;
    // prefetch next chunk into other buffer (overlaps with compute below)
    if (c + 1 < NCH) {
      const int kb2 = (c + 1) * 64;
#pragma unroll
      for (int i = 0; i < 2; ++i) {
        const int base = (i * 4 + w) * 512;
        const int row = (i * 4 + w) * 8 + st_row;
        GLOAD_LDS16(xb_b + (size_t)(kb2 + row) * DD + st_j * 8, &sK[cur ^ 1][base]);
        GLOAD_LDS16(xT_b + (size_t)row * NN + kb2 + st_j * 8, &sV[cur ^ 1][base]);
      }
    }

    // adjacency: 64 key-bits per q-row; pre-shift by quad*4
    unsigned wlo[4], whi[4];
#pragma unroll
    for (int qt = 0; qt < 4; ++qt) {
      unsigned long long a =
          adjb[(size_t)(qbase + qt * 16 + lane16) * (NN / 64) + c];
      a >>= (quad * 4);
      wlo[qt] = (unsigned)a;
      whi[qt] = (unsigned)(a >> 32);
    }

    const short* sKc = sK[cur];
    const short* sVc = sV[cur];

#pragma unroll
    for (int nt = 0; nt < 4; ++nt) {
      // S^T tile (keys nt*16.., q qt*16..): D[m=key][n=q]
      f32x4 s[4] = {{0.f, 0.f, 0.f, 0.f}, {0.f, 0.f, 0.f, 0.f},
                    {0.f, 0.f, 0.f, 0.f}, {0.f, 0.f, 0.f, 0.f}};
#pragma unroll
      for (int ks = 0; ks < 2; ++ks) {
        const int jb = (ks * 4 + quad) ^ (lane16 & 7);
        short8 kf = *(const short8*)&sKc[(nt * 16 + lane16) * 64 + jb * 8];
#pragma unroll
        for (int qt = 0; qt < 4; ++qt)
          s[qt] = __builtin_amdgcn_mfma_f32_16x16x32_bf16(kf, qf[qt][ks], s[qt], 0, 0, 0);
      }

      // masked exp2 -> P^T in registers (C-layout == x16 B-frag layout)
      short4v pf[4];
#pragma unroll
      for (int qt = 0; qt < 4; ++qt) {
        const unsigned wb = (nt < 2) ? wlo[qt] : whi[qt];
#pragma unroll
        for (int r = 0; r < 4; ++r) {
          const unsigned bit = (wb >> ((nt & 1) * 16 + r)) & 1u;
          float ein = bit ? s[qt][r] : -1e12f;  // exp2(-1e12) == 0
          float p = fast_exp2(ein);
          lpart[qt] += p;
          pf[qt][r] = f2bf(p);
        }
      }

      // O^T += V^T P^T  (A = V^T frag from LDS, B = pf from registers)
#pragma unroll
      for (int dt = 0; dt < 4; ++dt) {
        const int jb2 = (nt * 2 + (quad >> 1)) ^ (lane16 & 7);
        short4v vf = *(const short4v*)&sVc[(dt * 16 + lane16) * 64 + jb2 * 8 +
                                           (quad & 1) * 4];
#pragma unroll
        for (int qt = 0; qt < 4; ++qt)
          acc[qt][dt] = MFMA16(vf, pf[qt], acc[qt][dt]);
      }
    }
    __syncthreads();  // buf[cur] consumed; next iter may overwrite it
  }

  // ---- epilogue: l-reduce across quads, scale, store ----
#pragma unroll
  for (int qt = 0; qt < 4; ++qt) {
    float lq = lpart[qt];
    lq += __shfl_xor(lq, 16, 64);
    lq += __shfl_xor(lq, 32, 64);
    const float inv = 1.0f / lq;
    float* op =
        out + ((size_t)b * NN + qbase + qt * 16 + lane16) * DD + quad * 4;
#pragma unroll
    for (int dt = 0; dt < 4; ++dt) {
      float4 o;
      o.x = acc[qt][dt][0] * inv;
      o.y = acc[qt][dt][1] * inv;
      o.z = acc[qt][dt][2] * inv;
      o.w = acc[qt][dt][3] * inv;
      *(float4*)(op + dt * 16) = o;
    }
  }
}

extern "C" void kernel_launch(void* const* d_in, const int* in_sizes, int n_in,
                              void* d_out, int out_size, void* d_ws,
                              size_t ws_size, hipStream_t stream) {
  const float* x = (const float*)d_in[0];
  const int* adj = (const int*)d_in[1];
  float* out = (float*)d_out;

  short* xbf = (short*)d_ws;                             // 8 MB
  short* xT = xbf + (size_t)NB * NN * DD;                // 8 MB
  unsigned long long* adjb =
      (unsigned long long*)(xT + (size_t)NB * NN * DD);  // 512 KB

  prep_x<<<dim3(NN / 64, NB), 256, 0, stream>>>(x, xbf, xT);
  prep_adj<<<(NN * NN) / 256, 256, 0, stream>>>(adj, adjb);
  gat_flash3<<<dim3(NN / 256, NB), 256, 0, stream>>>(x, xbf, xT, adjb, out);
}

// Round 5
// 161.265 us; speedup vs baseline: 2.0381x; 1.1967x over previous
//
#include <hip/hip_runtime.h>
#include <hip/hip_bf16.h>

#define NB 32
#define NN 2048
#define DD 64
#define NCH 32
#define LOG2E 1.44269504088896340736f

typedef __attribute__((ext_vector_type(8))) short short8;
typedef __attribute__((ext_vector_type(4))) short short4v;
typedef __attribute__((ext_vector_type(4))) float f32x4;

// v_mfma_f32_16x16x16_bf16 (A/B = 4 bf16). Direct call, no #error guards.
#define MFMA16(A, B, C) \
  __builtin_amdgcn_mfma_f32_16x16x16bf16_1k((A), (B), (C), 0, 0, 0)

#define GLOAD_LDS16(gp, lp)                                                   \
  __builtin_amdgcn_global_load_lds(                                          \
      (const __attribute__((address_space(1))) void*)(gp),                   \
      (__attribute__((address_space(3))) void*)(lp), 16, 0, 0)

__device__ __forceinline__ short f2bf(float x) {
  __bf16 h = (__bf16)x;
  return __builtin_bit_cast(short, h);
}

// Raw v_exp_f32 (no libm range fixup). Guard is preprocessor-safe: host pass
// simply takes the exp2f branch; device pass picks the intrinsic.
__device__ __forceinline__ float fast_exp2(float x) {
#if __has_builtin(__builtin_amdgcn_exp2f)
  return __builtin_amdgcn_exp2f(x);
#else
  return exp2f(x);
#endif
}

// ---------- prep 1: x fp32 -> xbf (row-major bf16) + xT (per-batch [D][N] bf16)
__global__ __launch_bounds__(256) void prep_x(const float* __restrict__ x,
                                              short* __restrict__ xbf,
                                              short* __restrict__ xT) {
  __shared__ short t[64 * 72];
  const int tid = threadIdx.x;
  const int n0 = blockIdx.x * 64;
  const int b = blockIdx.y;
  const int r = tid >> 2;
  const int cg = tid & 3;

  const float* src = x + ((size_t)b * NN + n0 + r) * DD + cg * 16;
  short8 v[2];
#pragma unroll
  for (int h = 0; h < 2; ++h) {
    float4 f0 = ((const float4*)src)[h * 2];
    float4 f1 = ((const float4*)src)[h * 2 + 1];
    short8 a;
    a[0] = f2bf(f0.x); a[1] = f2bf(f0.y); a[2] = f2bf(f0.z); a[3] = f2bf(f0.w);
    a[4] = f2bf(f1.x); a[5] = f2bf(f1.y); a[6] = f2bf(f1.z); a[7] = f2bf(f1.w);
    v[h] = a;
  }
  short* dst = xbf + ((size_t)b * NN + n0 + r) * DD + cg * 16;
  ((short8*)dst)[0] = v[0];
  ((short8*)dst)[1] = v[1];
  *(short8*)&t[r * 72 + cg * 16] = v[0];
  *(short8*)&t[r * 72 + cg * 16 + 8] = v[1];
  __syncthreads();
  short8 o0, o1;
#pragma unroll
  for (int i = 0; i < 8; ++i) o0[i] = t[(cg * 16 + i) * 72 + r];
#pragma unroll
  for (int i = 0; i < 8; ++i) o1[i] = t[(cg * 16 + 8 + i) * 72 + r];
  short* dstT = xT + ((size_t)b * DD + r) * NN + n0 + cg * 16;
  ((short8*)dstT)[0] = o0;
  ((short8*)dstT)[1] = o1;
}

// ---------- prep 2: adj int32 -> bitmask
__global__ __launch_bounds__(256) void prep_adj(const int* __restrict__ adj,
                                                unsigned long long* __restrict__ bits) {
  const int i = blockIdx.x * 256 + threadIdx.x;
  unsigned long long m = __ballot(adj[i] > 0);
  if ((threadIdx.x & 63) == 0) bits[i >> 6] = m;
}

// ---------- main: 8 waves x 32 q-rows = 256 q-rows/block; 2 waves/SIMD.
// S^T formulation, shared LDS K/V staging (swizzled), register-only P,
// l-sum via all-ones MFMA.
__global__ __launch_bounds__(512, 2) void gat_flash4(
    const float* __restrict__ x, const short* __restrict__ xbf,
    const short* __restrict__ xT, const unsigned long long* __restrict__ adjb,
    float* __restrict__ out) {
  __shared__ short sK[2][64 * 64];  // swizzled: 16B block pos p holds j = p ^ (row&7)
  __shared__ short sV[2][64 * 64];

  const int tid = threadIdx.x;
  const int w = tid >> 6;          // 0..7
  const int l = tid & 63;
  const int lane16 = l & 15;
  const int quad = l >> 4;
  const int b = blockIdx.y;
  const int qbase = blockIdx.x * 256 + w * 32;

  const short* xb_b = xbf + (size_t)b * NN * DD;
  const short* xT_b = xT + (size_t)b * DD * NN;

  // staging geometry: wave w covers rows w*8..w*8+7 of the 64-row chunk
  const int st_row = (l >> 3);
  const int st_j = (l & 7) ^ (l >> 3);

  // ---- Q B-frags (n=lane16=q, k=quad*8+j=d), pre-scaled by (1/8)*log2e ----
  const float qs = 0.125f * LOG2E;
  short8 qf[2][2];
#pragma unroll
  for (int qt = 0; qt < 2; ++qt) {
    const float* qp = x + ((size_t)b * NN + qbase + qt * 16 + lane16) * DD;
#pragma unroll
    for (int ks = 0; ks < 2; ++ks) {
      float4 v0 = *(const float4*)(qp + ks * 32 + quad * 8);
      float4 v1 = *(const float4*)(qp + ks * 32 + quad * 8 + 4);
      short8 a;
      a[0] = f2bf(v0.x * qs); a[1] = f2bf(v0.y * qs);
      a[2] = f2bf(v0.z * qs); a[3] = f2bf(v0.w * qs);
      a[4] = f2bf(v1.x * qs); a[5] = f2bf(v1.y * qs);
      a[6] = f2bf(v1.z * qs); a[7] = f2bf(v1.w * qs);
      qf[qt][ks] = a;
    }
  }

  f32x4 acc[2][4];   // [qt][dt] O^T tiles: row=d=quad*4+reg, col=q=lane16
  f32x4 acc_l[2];    // l-sums: every row = l[q=lane16]
#pragma unroll
  for (int qt = 0; qt < 2; ++qt) {
    acc_l[qt] = {0.f, 0.f, 0.f, 0.f};
#pragma unroll
    for (int dt = 0; dt < 4; ++dt) acc[qt][dt] = {0.f, 0.f, 0.f, 0.f};
  }

  short4v ones;
  ones[0] = 0x3F80; ones[1] = 0x3F80; ones[2] = 0x3F80; ones[3] = 0x3F80;

  // ---- stage chunk 0 into buf 0 (wave w: 1KB of K + 1KB of V) ----
  GLOAD_LDS16(xb_b + (size_t)(w * 8 + st_row) * DD + st_j * 8, &sK[0][w * 512]);
  GLOAD_LDS16(xT_b + (size_t)(w * 8 + st_row) * NN + st_j * 8, &sV[0][w * 512]);
  __syncthreads();

  for (int c = 0; c < NCH; ++c) {
    const int cur = c & 1;
    if (c + 1 < NCH) {
      const int kb2 = (c + 1) * 64;
      GLOAD_LDS16(xb_b + (size_t)(kb2 + w * 8 + st_row) * DD + st_j * 8,
                  &sK[cur ^ 1][w * 512]);
      GLOAD_LDS16(xT_b + (size_t)(w * 8 + st_row) * NN + kb2 + st_j * 8,
                  &sV[cur ^ 1][w * 512]);
    }

    // adjacency: 64 key-bits per q-row; pre-shift by quad*4
    unsigned wlo[2], whi[2];
#pragma unroll
    for (int qt = 0; qt < 2; ++qt) {
      unsigned long long a =
          adjb[(size_t)(qbase + qt * 16 + lane16) * (NN / 64) + c];
      a >>= (quad * 4);
      wlo[qt] = (unsigned)a;
      whi[qt] = (unsigned)(a >> 32);
    }

    const short* sKc = sK[cur];
    const short* sVc = sV[cur];

#pragma unroll
    for (int nt = 0; nt < 4; ++nt) {
      // S^T tile (keys nt*16.., q qt*16..): D[m=key][n=q]
      f32x4 s[2] = {{0.f, 0.f, 0.f, 0.f}, {0.f, 0.f, 0.f, 0.f}};
#pragma unroll
      for (int ks = 0; ks < 2; ++ks) {
        const int jb = (ks * 4 + quad) ^ (lane16 & 7);
        short8 kf = *(const short8*)&sKc[(nt * 16 + lane16) * 64 + jb * 8];
#pragma unroll
        for (int qt = 0; qt < 2; ++qt)
          s[qt] = __builtin_amdgcn_mfma_f32_16x16x32_bf16(kf, qf[qt][ks], s[qt], 0, 0, 0);
      }

      // exp2 first (trans pipe), then mask-to-zero -> P^T in registers
      short4v pf[2];
#pragma unroll
      for (int qt = 0; qt < 2; ++qt) {
        const unsigned wb = (nt < 2) ? wlo[qt] : whi[qt];
#pragma unroll
        for (int r = 0; r < 4; ++r) {
          const unsigned bit = (wb >> ((nt & 1) * 16 + r)) & 1u;
          float e = fast_exp2(s[qt][r]);
          float p = bit ? e : 0.f;
          pf[qt][r] = f2bf(p);
        }
      }

      // l += ones * P^T (one MFMA per qt; every D row = sum over keys)
#pragma unroll
      for (int qt = 0; qt < 2; ++qt)
        acc_l[qt] = MFMA16(ones, pf[qt], acc_l[qt]);

      // O^T += V^T P^T  (A = V^T frag from LDS, B = pf from registers)
#pragma unroll
      for (int dt = 0; dt < 4; ++dt) {
        const int jb2 = (nt * 2 + (quad >> 1)) ^ (lane16 & 7);
        short4v vf = *(const short4v*)&sVc[(dt * 16 + lane16) * 64 + jb2 * 8 +
                                           (quad & 1) * 4];
#pragma unroll
        for (int qt = 0; qt < 2; ++qt)
          acc[qt][dt] = MFMA16(vf, pf[qt], acc[qt][dt]);
      }
    }
    __syncthreads();  // buf[cur] consumed; next iter overwrites it
  }

  // ---- epilogue: every lane already holds l[q=lane16] in acc_l[qt][0] ----
#pragma unroll
  for (int qt = 0; qt < 2; ++qt) {
    const float inv = 1.0f / acc_l[qt][0];
    float* op =
        out + ((size_t)b * NN + qbase + qt * 16 + lane16) * DD + quad * 4;
#pragma unroll
    for (int dt = 0; dt < 4; ++dt) {
      float4 o;
      o.x = acc[qt][dt][0] * inv;
      o.y = acc[qt][dt][1] * inv;
      o.z = acc[qt][dt][2] * inv;
      o.w = acc[qt][dt][3] * inv;
      *(float4*)(op + dt * 16) = o;
    }
  }
}

extern "C" void kernel_launch(void* const* d_in, const int* in_sizes, int n_in,
                              void* d_out, int out_size, void* d_ws,
                              size_t ws_size, hipStream_t stream) {
  const float* x = (const float*)d_in[0];
  const int* adj = (const int*)d_in[1];
  float* out = (float*)d_out;

  short* xbf = (short*)d_ws;                             // 8 MB
  short* xT = xbf + (size_t)NB * NN * DD;                // 8 MB
  unsigned long long* adjb =
      (unsigned long long*)(xT + (size_t)NB * NN * DD);  // 512 KB

  prep_x<<<dim3(NN / 64, NB), 256, 0, stream>>>(x, xbf, xT);
  prep_adj<<<(NN * NN) / 256, 256, 0, stream>>>(adj, adjb);
  gat_flash4<<<dim3(NN / 256, NB), 512, 0, stream>>>(x, xbf, xT, adjb, out);
}